// Round 4
// baseline (767.367 us; speedup 1.0000x reference)
//
#include <hip/hip_runtime.h>
#include <math.h>

#define NEG_SLOPE 0.2f

// ---------------------------------------------------------------- CSR build
__global__ void deg_count_kernel(const int* __restrict__ dst, int* __restrict__ deg, int E){
  int e = blockIdx.x * blockDim.x + threadIdx.x;
  if (e < E) atomicAdd(&deg[dst[e]], 1);
}

__global__ void base_assign_kernel(const int* __restrict__ deg, int* __restrict__ base,
                                   int* __restrict__ counter, int N){
  int n = blockIdx.x * blockDim.x + threadIdx.x;
  if (n < N) base[n] = atomicAdd(counter, deg[n]);
}

__global__ void fill_kernel(const int* __restrict__ ei, const float* __restrict__ ea,
                            const int* __restrict__ base, int* __restrict__ pos,
                            int2* __restrict__ csr_pack, int E){
  int e = blockIdx.x * blockDim.x + threadIdx.x;
  if (e >= E) return;
  int s = ei[e], d = ei[E + e];
  int p = atomicAdd(&pos[d], 1);
  csr_pack[base[d] + p] = make_int2(s, __float_as_int(ea[e]));
}

// ---------------------------------------------------------------- dual GEMM, 8x8 thread tile
// Y1 = X@W1+b1, Y2 = X@W2+b2 in one block. 128 threads; thread = 8 rows x 4 cols x both W.
// LDS balance: 16 b128 reads per 256 FMA -> LDS supply == VALU demand.
template<int M, int K>
__global__ __launch_bounds__(128) void gemm_dual_kernel(
    const float* __restrict__ X,
    const float* __restrict__ W1, const float* __restrict__ b1,
    const float* __restrict__ W2, const float* __restrict__ b2,
    float* __restrict__ Y1, float* __restrict__ Y2, int N)
{
  constexpr int CG   = M / 4;          // col groups: 32 (M=128) or 16 (M=64)
  constexpr int RG   = 128 / CG;       // row groups: 4 or 8
  constexpr int TR   = RG * 8;         // rows per block: 32 or 64
  constexpr int SLAB = 16;
  __shared__ float xs [TR * SLAB];
  __shared__ float ws1[SLAB * M];
  __shared__ float ws2[SLAB * M];

  int tid = threadIdx.x;
  int r0  = blockIdx.x * TR;
  int cg  = tid % CG, rg = tid / CG;
  int col = cg * 4;

  float acc1[8][4], acc2[8][4];
  #pragma unroll
  for (int i = 0; i < 8; i++)
    #pragma unroll
    for (int j = 0; j < 4; j++){ acc1[i][j] = 0.f; acc2[i][j] = 0.f; }

  for (int k0 = 0; k0 < K; k0 += SLAB){
    if (k0) __syncthreads();           // WAR on LDS from previous slab
    // stage X slab (TR rows x SLAB k)
    constexpr int CH = SLAB / 4;
    for (int q = tid; q < TR * CH; q += 128){
      int r = q / CH, ch = (q % CH) * 4;
      int grow = r0 + r, kg = k0 + ch;
      float4 v = {0.f,0.f,0.f,0.f};
      if (grow < N){
        if constexpr (K % 4 == 0){
          v = *(const float4*)(X + (long)grow * K + kg);
        } else {
          const float* px = X + (long)grow * K;
          if (kg + 0 < K) v.x = px[kg + 0];
          if (kg + 1 < K) v.y = px[kg + 1];
          if (kg + 2 < K) v.z = px[kg + 2];
          if (kg + 3 < K) v.w = px[kg + 3];
        }
      }
      *(float4*)&xs[r * SLAB + ch] = v;
    }
    // stage W1/W2 slabs (SLAB k x M)
    for (int q = tid; q < SLAB * M / 4; q += 128){
      int kk = q / (M / 4), cc = (q % (M / 4)) * 4;
      int k = k0 + kk;
      float4 v1 = {0.f,0.f,0.f,0.f}, v2 = {0.f,0.f,0.f,0.f};
      if (k < K){
        v1 = *(const float4*)(W1 + (long)k * M + cc);
        v2 = *(const float4*)(W2 + (long)k * M + cc);
      }
      *(float4*)&ws1[kk * M + cc] = v1;
      *(float4*)&ws2[kk * M + cc] = v2;
    }
    __syncthreads();
    #pragma unroll
    for (int kb = 0; kb < SLAB; kb += 4){
      float4 xv[8];
      #pragma unroll
      for (int i = 0; i < 8; i++)
        xv[i] = *(const float4*)&xs[(rg * 8 + i) * SLAB + kb];
      #pragma unroll
      for (int t = 0; t < 4; t++){
        float4 u1 = *(const float4*)&ws1[(kb + t) * M + col];
        float4 u2 = *(const float4*)&ws2[(kb + t) * M + col];
        #pragma unroll
        for (int i = 0; i < 8; i++){
          float a = (t == 0) ? xv[i].x : (t == 1) ? xv[i].y : (t == 2) ? xv[i].z : xv[i].w;
          acc1[i][0] += a * u1.x; acc1[i][1] += a * u1.y;
          acc1[i][2] += a * u1.z; acc1[i][3] += a * u1.w;
          acc2[i][0] += a * u2.x; acc2[i][1] += a * u2.y;
          acc2[i][2] += a * u2.z; acc2[i][3] += a * u2.w;
        }
      }
    }
  }
  float4 bv1 = *(const float4*)&b1[col];
  float4 bv2 = *(const float4*)&b2[col];
  #pragma unroll
  for (int i = 0; i < 8; i++){
    int row = r0 + rg * 8 + i;
    if (row < N){
      float4 o1 = make_float4(acc1[i][0]+bv1.x, acc1[i][1]+bv1.y, acc1[i][2]+bv1.z, acc1[i][3]+bv1.w);
      float4 o2 = make_float4(acc2[i][0]+bv2.x, acc2[i][1]+bv2.y, acc2[i][2]+bv2.z, acc2[i][3]+bv2.w);
      *(float4*)&Y1[(long)row * M + col] = o1;
      *(float4*)&Y2[(long)row * M + col] = o2;
    }
  }
}

// ---------------------------------------------------------------- fused edge softmax + aggregation
// one wave per dst node. Lane = (edge-slot e=lane>>3, head h=lane&7); each lane owns
// all C channels of head h for edge-slot e. In-lane head dot (no per-edge shfl),
// one exp per lane per batch, lane-local weighted partial sums reduced once at end.
template<int C>
__global__ __launch_bounds__(256) void agg_kernel(
    const float* __restrict__ xl, const float* __restrict__ xr,
    const int* __restrict__ base, const int* __restrict__ deg,
    const int2* __restrict__ csr_pack,
    const float* __restrict__ We, const float* __restrict__ att,
    const float* __restrict__ bias, float* __restrict__ hout,
    int N, int do_elu)
{
  constexpr int HC = 8 * C;
  int lane = threadIdx.x & 63;
  int n = (blockIdx.x * blockDim.x + threadIdx.x) >> 6;
  if (n >= N) return;
  int e8 = lane >> 3;          // edge slot 0..7
  int h  = lane & 7;           // head 0..7
  int c0 = h * C;

  float attv[C], wev[C], xrv[C], acc[C];
  #pragma unroll
  for (int q = 0; q < C / 4; q++){
    float4 a4 = *(const float4*)(att + c0 + 4 * q);
    float4 w4 = *(const float4*)(We  + c0 + 4 * q);
    float4 x4 = *(const float4*)(xr + (long)n * HC + c0 + 4 * q);
    attv[4*q+0]=a4.x; attv[4*q+1]=a4.y; attv[4*q+2]=a4.z; attv[4*q+3]=a4.w;
    wev [4*q+0]=w4.x; wev [4*q+1]=w4.y; wev [4*q+2]=w4.z; wev [4*q+3]=w4.w;
    xrv [4*q+0]=x4.x; xrv [4*q+1]=x4.y; xrv [4*q+2]=x4.z; xrv [4*q+3]=x4.w;
    acc [4*q+0]=0.f;  acc [4*q+1]=0.f;  acc [4*q+2]=0.f;  acc [4*q+3]=0.f;
  }

  int s0 = base[n], end = s0 + deg[n];
  float mrun = -INFINITY, lrun = 0.f;

  for (int s = s0; s < end; s += 8){
    int  slot  = s + e8;
    bool valid = slot < end;
    int2 pk = csr_pack[valid ? slot : s0];
    int   srcn = pk.x;
    float eav  = __int_as_float(pk.y);

    float xlv[C];
    const float4* prow = (const float4*)(xl + (long)srcn * HC + c0);
    #pragma unroll
    for (int q = 0; q < C / 4; q++){
      float4 v = prow[q];
      xlv[4*q+0]=v.x; xlv[4*q+1]=v.y; xlv[4*q+2]=v.z; xlv[4*q+3]=v.w;
    }
    // in-lane head dot with 2 partial chains
    float p0 = 0.f, p1 = 0.f;
    #pragma unroll
    for (int c = 0; c < C; c += 2){
      float t0 = xlv[c]   + xrv[c]   + eav * wev[c];
      float t1 = xlv[c+1] + xrv[c+1] + eav * wev[c+1];
      float m0 = fmaxf(t0, 0.f) + NEG_SLOPE * fminf(t0, 0.f);
      float m1 = fmaxf(t1, 0.f) + NEG_SLOPE * fminf(t1, 0.f);
      p0 += m0 * attv[c];
      p1 += m1 * attv[c+1];
    }
    float p = valid ? (p0 + p1) : -INFINITY;
    // head-max over the 8 edge-slot lanes of this head
    float bm = p;
    bm = fmaxf(bm, __shfl_xor(bm, 8));
    bm = fmaxf(bm, __shfl_xor(bm, 16));
    bm = fmaxf(bm, __shfl_xor(bm, 32));
    float newm = fmaxf(mrun, bm);
    float sc = __expf(mrun - newm);     // first batch: exp(-inf)=0
    float pe = __expf(p - newm);        // invalid: exp(-inf)=0
    lrun = lrun * sc + pe;
    #pragma unroll
    for (int c = 0; c < C; c++)
      acc[c] = acc[c] * sc + pe * xlv[c];
    mrun = newm;
  }

  // reduce partial sums across the 8 edge-slot lanes (same head)
  float lsum = lrun;
  lsum += __shfl_xor(lsum, 8);
  lsum += __shfl_xor(lsum, 16);
  lsum += __shfl_xor(lsum, 32);
  #pragma unroll
  for (int c = 0; c < C; c++){
    acc[c] += __shfl_xor(acc[c], 8);
    acc[c] += __shfl_xor(acc[c], 16);
    acc[c] += __shfl_xor(acc[c], 32);
  }
  float inv = 1.f / (lsum + 1e-16f);
  if (e8 == 0){
    #pragma unroll
    for (int q = 0; q < C / 4; q++){
      float4 b4 = *(const float4*)(bias + c0 + 4 * q);
      float4 o;
      o.x = acc[4*q+0] * inv + b4.x;
      o.y = acc[4*q+1] * inv + b4.y;
      o.z = acc[4*q+2] * inv + b4.z;
      o.w = acc[4*q+3] * inv + b4.w;
      if (do_elu){
        o.x = o.x > 0.f ? o.x : (__expf(o.x) - 1.f);
        o.y = o.y > 0.f ? o.y : (__expf(o.y) - 1.f);
        o.z = o.z > 0.f ? o.z : (__expf(o.z) - 1.f);
        o.w = o.w > 0.f ? o.w : (__expf(o.w) - 1.f);
      }
      *(float4*)(hout + (long)n * HC + c0 + 4 * q) = o;
    }
  }
}

// ---------------------------------------------------------------- final linear 64 -> 1, one wave per node
__global__ __launch_bounds__(256) void final_linear_kernel(
    const float* __restrict__ h, const float* __restrict__ Wlin,
    const float* __restrict__ blin, float* __restrict__ out, int N)
{
  int lane = threadIdx.x & 63;
  int n = (blockIdx.x * blockDim.x + threadIdx.x) >> 6;
  if (n >= N) return;
  float v = h[(long)n * 64 + lane] * Wlin[lane];
  #pragma unroll
  for (int off = 1; off < 64; off <<= 1) v += __shfl_xor(v, off);
  if (lane == 0) out[n] = v + blin[0];
}

// ----------------------------------------------------------------
extern "C" void kernel_launch(void* const* d_in, const int* in_sizes, int n_in,
                              void* d_out, int out_size, void* d_ws, size_t ws_size,
                              hipStream_t stream)
{
  const float* x  = (const float*)d_in[0];
  const float* ea = (const float*)d_in[1];
  const int*   ei = (const int*)d_in[2];
  const int N = in_sizes[0] / 15;
  const int E = in_sizes[1];

  const float* P[28];
  for (int i = 0; i < 28; i++) P[i] = (const float*)d_in[3 + i];
  const float* Wlin = (const float*)d_in[31];
  const float* blin = (const float*)d_in[32];

  size_t off = 0;
  auto carve = [&](size_t bytes) -> char* {
    char* p = (char*)d_ws + off;
    off = (off + bytes + 255) & ~(size_t)255;
    return p;
  };
  int*   meta     = (int*)  carve(sizeof(int)  * (size_t)(3 * N + 64));
  int*   deg      = meta;                // [N] zeroed
  int*   pos      = meta + N;            // [N] zeroed
  int*   base     = meta + 2 * N;        // [N]
  int*   counter  = meta + 3 * N;        // [1] zeroed
  int2*  csr_pack = (int2*) carve(sizeof(int2) * (size_t)E);
  float* xl       = (float*)carve(sizeof(float) * (size_t)N * 128);
  float* xr       = (float*)carve(sizeof(float) * (size_t)N * 128);
  float* hA       = (float*)carve(sizeof(float) * (size_t)N * 128);
  float* hB       = (float*)carve(sizeof(float) * (size_t)N * 128);

  hipMemsetAsync(deg,     0, sizeof(int) * (size_t)(2 * N), stream);
  hipMemsetAsync(counter, 0, sizeof(int), stream);

  int eb = (E + 255) / 256;
  int nb = (N + 255) / 256;
  deg_count_kernel  <<<eb, 256, 0, stream>>>(ei + E, deg, E);
  base_assign_kernel<<<nb, 256, 0, stream>>>(deg, base, counter, N);
  fill_kernel       <<<eb, 256, 0, stream>>>(ei, ea, base, pos, csr_pack, E);

  int g128 = (N + 31) / 32;   // M=128: 32-row tiles
  int g64  = (N + 63) / 64;   // M=64:  64-row tiles
  int ab   = (N + 3) / 4;     // agg/final: 4 waves per block

  // layer 1: din=15, H*C=128, ELU
  gemm_dual_kernel<128, 15><<<g128, 128, 0, stream>>>(x, P[0], P[1], P[2], P[3], xl, xr, N);
  agg_kernel<16><<<ab, 256, 0, stream>>>(xl, xr, base, deg, csr_pack, P[4], P[5], P[6], hA, N, 1);
  // layer 2: din=128, ELU
  gemm_dual_kernel<128, 128><<<g128, 128, 0, stream>>>(hA, P[7], P[8], P[9], P[10], xl, xr, N);
  agg_kernel<16><<<ab, 256, 0, stream>>>(xl, xr, base, deg, csr_pack, P[11], P[12], P[13], hB, N, 1);
  // layer 3: din=128, ELU
  gemm_dual_kernel<128, 128><<<g128, 128, 0, stream>>>(hB, P[14], P[15], P[16], P[17], xl, xr, N);
  agg_kernel<16><<<ab, 256, 0, stream>>>(xl, xr, base, deg, csr_pack, P[18], P[19], P[20], hA, N, 1);
  // layer 4: din=128, H*C=64, no ELU
  gemm_dual_kernel<64, 128><<<g64, 128, 0, stream>>>(hA, P[21], P[22], P[23], P[24], xl, xr, N);
  agg_kernel<8><<<ab, 256, 0, stream>>>(xl, xr, base, deg, csr_pack, P[25], P[26], P[27], hB, N, 0);
  // final linear 64 -> 1
  final_linear_kernel<<<ab, 256, 0, stream>>>(hB, Wlin, blin, (float*)d_out, N);
}

// Round 5
// 632.144 us; speedup vs baseline: 1.2139x; 1.2139x over previous
//
#include <hip/hip_runtime.h>
#include <math.h>

#define NEG_SLOPE 0.2f

// ---------------------------------------------------------------- CSR build
__global__ void deg_count_kernel(const int* __restrict__ dst, int* __restrict__ deg, int E){
  int e = blockIdx.x * blockDim.x + threadIdx.x;
  if (e < E) atomicAdd(&deg[dst[e]], 1);
}

__global__ void base_assign_kernel(const int* __restrict__ deg, int* __restrict__ base,
                                   int* __restrict__ counter, int N){
  int n = blockIdx.x * blockDim.x + threadIdx.x;
  if (n < N) base[n] = atomicAdd(counter, deg[n]);
}

__global__ void fill_kernel(const int* __restrict__ ei, const float* __restrict__ ea,
                            const int* __restrict__ base, int* __restrict__ pos,
                            int2* __restrict__ csr_pack, int E){
  int e = blockIdx.x * blockDim.x + threadIdx.x;
  if (e >= E) return;
  int s = ei[e], d = ei[E + e];
  int p = atomicAdd(&pos[d], 1);
  csr_pack[base[d] + p] = make_int2(s, __float_as_int(ea[e]));
}

// ---------------------------------------------------------------- dual GEMM, 8x8 thread tile (unchanged from R4)
template<int M, int K>
__global__ __launch_bounds__(128) void gemm_dual_kernel(
    const float* __restrict__ X,
    const float* __restrict__ W1, const float* __restrict__ b1,
    const float* __restrict__ W2, const float* __restrict__ b2,
    float* __restrict__ Y1, float* __restrict__ Y2, int N)
{
  constexpr int CG   = M / 4;          // col groups: 32 (M=128) or 16 (M=64)
  constexpr int RG   = 128 / CG;       // row groups: 4 or 8
  constexpr int TR   = RG * 8;         // rows per block: 32 or 64
  constexpr int SLAB = 16;
  __shared__ float xs [TR * SLAB];
  __shared__ float ws1[SLAB * M];
  __shared__ float ws2[SLAB * M];

  int tid = threadIdx.x;
  int r0  = blockIdx.x * TR;
  int cg  = tid % CG, rg = tid / CG;
  int col = cg * 4;

  float acc1[8][4], acc2[8][4];
  #pragma unroll
  for (int i = 0; i < 8; i++)
    #pragma unroll
    for (int j = 0; j < 4; j++){ acc1[i][j] = 0.f; acc2[i][j] = 0.f; }

  for (int k0 = 0; k0 < K; k0 += SLAB){
    if (k0) __syncthreads();
    constexpr int CH = SLAB / 4;
    for (int q = tid; q < TR * CH; q += 128){
      int r = q / CH, ch = (q % CH) * 4;
      int grow = r0 + r, kg = k0 + ch;
      float4 v = {0.f,0.f,0.f,0.f};
      if (grow < N){
        if constexpr (K % 4 == 0){
          v = *(const float4*)(X + (long)grow * K + kg);
        } else {
          const float* px = X + (long)grow * K;
          if (kg + 0 < K) v.x = px[kg + 0];
          if (kg + 1 < K) v.y = px[kg + 1];
          if (kg + 2 < K) v.z = px[kg + 2];
          if (kg + 3 < K) v.w = px[kg + 3];
        }
      }
      *(float4*)&xs[r * SLAB + ch] = v;
    }
    for (int q = tid; q < SLAB * M / 4; q += 128){
      int kk = q / (M / 4), cc = (q % (M / 4)) * 4;
      int k = k0 + kk;
      float4 v1 = {0.f,0.f,0.f,0.f}, v2 = {0.f,0.f,0.f,0.f};
      if (k < K){
        v1 = *(const float4*)(W1 + (long)k * M + cc);
        v2 = *(const float4*)(W2 + (long)k * M + cc);
      }
      *(float4*)&ws1[kk * M + cc] = v1;
      *(float4*)&ws2[kk * M + cc] = v2;
    }
    __syncthreads();
    #pragma unroll
    for (int kb = 0; kb < SLAB; kb += 4){
      float4 xv[8];
      #pragma unroll
      for (int i = 0; i < 8; i++)
        xv[i] = *(const float4*)&xs[(rg * 8 + i) * SLAB + kb];
      #pragma unroll
      for (int t = 0; t < 4; t++){
        float4 u1 = *(const float4*)&ws1[(kb + t) * M + col];
        float4 u2 = *(const float4*)&ws2[(kb + t) * M + col];
        #pragma unroll
        for (int i = 0; i < 8; i++){
          float a = (t == 0) ? xv[i].x : (t == 1) ? xv[i].y : (t == 2) ? xv[i].z : xv[i].w;
          acc1[i][0] += a * u1.x; acc1[i][1] += a * u1.y;
          acc1[i][2] += a * u1.z; acc1[i][3] += a * u1.w;
          acc2[i][0] += a * u2.x; acc2[i][1] += a * u2.y;
          acc2[i][2] += a * u2.z; acc2[i][3] += a * u2.w;
        }
      }
    }
  }
  float4 bv1 = *(const float4*)&b1[col];
  float4 bv2 = *(const float4*)&b2[col];
  #pragma unroll
  for (int i = 0; i < 8; i++){
    int row = r0 + rg * 8 + i;
    if (row < N){
      float4 o1 = make_float4(acc1[i][0]+bv1.x, acc1[i][1]+bv1.y, acc1[i][2]+bv1.z, acc1[i][3]+bv1.w);
      float4 o2 = make_float4(acc2[i][0]+bv2.x, acc2[i][1]+bv2.y, acc2[i][2]+bv2.z, acc2[i][3]+bv2.w);
      *(float4*)&Y1[(long)row * M + col] = o1;
      *(float4*)&Y2[(long)row * M + col] = o2;
    }
  }
}

// ---------------------------------------------------------------- fused edge softmax + aggregation
// One wave per dst node (grid-stride). Lane = (edge-slot, head, channel-quad):
// LPE = lanes per edge (32 for C=16, 16 for C=8) -> each row read is fully
// contiguous (512/256 B) b128 per lane. No-max softmax (logits O(1); exp is
// algebraically identical to ref's max-subtracted form) -> no cross-batch
// serial dependency, loads prefetch ahead. Optional fused final linear.
template<int C>
__global__ __launch_bounds__(512) void agg_kernel(
    const float* __restrict__ xl, const float* __restrict__ xr,
    const int* __restrict__ base, const int* __restrict__ deg,
    const int2* __restrict__ csr_pack,
    const float* __restrict__ We, const float* __restrict__ att,
    const float* __restrict__ bias, float* __restrict__ hout,
    const float* __restrict__ Wlin, const float* __restrict__ blin,
    float* __restrict__ outF, int N, int do_elu)
{
  constexpr int HC  = 8 * C;
  constexpr int LPH = C / 4;       // lanes per head
  constexpr int LPE = 8 * LPH;     // lanes per edge (32 or 16)
  constexpr int ES  = 64 / LPE;    // edge slots per pass (2 or 4)
  constexpr int NP  = 4;           // passes per iteration
  constexpr int B   = ES * NP;     // edges per iteration (8 or 16)

  int lane = threadIdx.x & 63;
  int wv   = blockIdx.x * (blockDim.x >> 6) + (threadIdx.x >> 6);
  int nwv  = gridDim.x * (blockDim.x >> 6);
  int slot = lane / LPE;           // edge slot within pass
  int hl   = lane % LPE;           // position within edge
  int coff = hl * 4;               // channel offset: h*C + g*4 == hl*4

  float4 attv = *(const float4*)(att  + coff);
  float4 wev  = *(const float4*)(We   + coff);
  float4 bv   = *(const float4*)(bias + coff);
  float4 wl   = outF ? *(const float4*)(Wlin + coff) : make_float4(0.f,0.f,0.f,0.f);

  for (int n = wv; n < N; n += nwv){
    float4 xrv = *(const float4*)(xr + (long)n * HC + coff);
    float4 acc = {0.f, 0.f, 0.f, 0.f};
    float lrun = 0.f;
    int s0 = base[n], end = s0 + deg[n];

    for (int s = s0; s < end; s += B){
      int2 pk[NP]; bool val[NP];
      #pragma unroll
      for (int t = 0; t < NP; t++){
        int idx = s + t * ES + slot;
        val[t] = idx < end;
        pk[t]  = csr_pack[val[t] ? idx : s0];
      }
      float4 row[NP];
      #pragma unroll
      for (int t = 0; t < NP; t++)
        row[t] = *(const float4*)(xl + (long)pk[t].x * HC + coff);
      #pragma unroll
      for (int t = 0; t < NP; t++){
        float eav = __int_as_float(pk[t].y);
        float t0 = row[t].x + xrv.x + eav * wev.x;
        float t1 = row[t].y + xrv.y + eav * wev.y;
        float t2 = row[t].z + xrv.z + eav * wev.z;
        float t3 = row[t].w + xrv.w + eav * wev.w;
        float m0 = fmaxf(t0, 0.f) + NEG_SLOPE * fminf(t0, 0.f);
        float m1 = fmaxf(t1, 0.f) + NEG_SLOPE * fminf(t1, 0.f);
        float m2 = fmaxf(t2, 0.f) + NEG_SLOPE * fminf(t2, 0.f);
        float m3 = fmaxf(t3, 0.f) + NEG_SLOPE * fminf(t3, 0.f);
        float p = ((m0 * attv.x + m1 * attv.y) + (m2 * attv.z + m3 * attv.w));
        #pragma unroll
        for (int o = 1; o < LPH; o <<= 1) p += __shfl_xor(p, o);
        float pe = val[t] ? __expf(p) : 0.f;
        lrun  += pe;
        acc.x += pe * row[t].x;
        acc.y += pe * row[t].y;
        acc.z += pe * row[t].z;
        acc.w += pe * row[t].w;
      }
    }
    // reduce over edge slots
    #pragma unroll
    for (int o = LPE; o < 64; o <<= 1){
      lrun  += __shfl_xor(lrun, o);
      acc.x += __shfl_xor(acc.x, o);
      acc.y += __shfl_xor(acc.y, o);
      acc.z += __shfl_xor(acc.z, o);
      acc.w += __shfl_xor(acc.w, o);
    }
    float inv = 1.f / (lrun + 1e-16f);
    float4 o4;
    o4.x = acc.x * inv + bv.x;
    o4.y = acc.y * inv + bv.y;
    o4.z = acc.z * inv + bv.z;
    o4.w = acc.w * inv + bv.w;
    if (do_elu){
      o4.x = o4.x > 0.f ? o4.x : (__expf(o4.x) - 1.f);
      o4.y = o4.y > 0.f ? o4.y : (__expf(o4.y) - 1.f);
      o4.z = o4.z > 0.f ? o4.z : (__expf(o4.z) - 1.f);
      o4.w = o4.w > 0.f ? o4.w : (__expf(o4.w) - 1.f);
    }
    if (outF){
      // fused final linear: out[n] = sum_c o_c * Wlin_c + blin
      float v = ((o4.x * wl.x + o4.y * wl.y) + (o4.z * wl.z + o4.w * wl.w));
      #pragma unroll
      for (int o = 1; o < LPE; o <<= 1) v += __shfl_xor(v, o);
      if (lane == 0) outF[n] = v + blin[0];
    } else {
      if (slot == 0)
        *(float4*)(hout + (long)n * HC + coff) = o4;
    }
  }
}

// ----------------------------------------------------------------
extern "C" void kernel_launch(void* const* d_in, const int* in_sizes, int n_in,
                              void* d_out, int out_size, void* d_ws, size_t ws_size,
                              hipStream_t stream)
{
  const float* x  = (const float*)d_in[0];
  const float* ea = (const float*)d_in[1];
  const int*   ei = (const int*)d_in[2];
  const int N = in_sizes[0] / 15;
  const int E = in_sizes[1];

  const float* P[28];
  for (int i = 0; i < 28; i++) P[i] = (const float*)d_in[3 + i];
  const float* Wlin = (const float*)d_in[31];
  const float* blin = (const float*)d_in[32];

  size_t off = 0;
  auto carve = [&](size_t bytes) -> char* {
    char* p = (char*)d_ws + off;
    off = (off + bytes + 255) & ~(size_t)255;
    return p;
  };
  int*   meta     = (int*)  carve(sizeof(int)  * (size_t)(3 * N + 64));
  int*   deg      = meta;                // [N] zeroed
  int*   pos      = meta + N;            // [N] zeroed
  int*   base     = meta + 2 * N;        // [N]
  int*   counter  = meta + 3 * N;        // [1] zeroed
  int2*  csr_pack = (int2*) carve(sizeof(int2) * (size_t)E);
  float* xl       = (float*)carve(sizeof(float) * (size_t)N * 128);
  float* xr       = (float*)carve(sizeof(float) * (size_t)N * 128);
  float* hA       = (float*)carve(sizeof(float) * (size_t)N * 128);
  float* hB       = (float*)carve(sizeof(float) * (size_t)N * 128);

  hipMemsetAsync(deg,     0, sizeof(int) * (size_t)(2 * N), stream);
  hipMemsetAsync(counter, 0, sizeof(int), stream);

  int eb = (E + 255) / 256;
  int nb = (N + 255) / 256;
  deg_count_kernel  <<<eb, 256, 0, stream>>>(ei + E, deg, E);
  base_assign_kernel<<<nb, 256, 0, stream>>>(deg, base, counter, N);
  fill_kernel       <<<eb, 256, 0, stream>>>(ei, ea, base, pos, csr_pack, E);

  int g128 = (N + 31) / 32;   // M=128: 32-row tiles
  int g64  = (N + 63) / 64;   // M=64:  64-row tiles
  int agrid = 2048;           // agg: grid-stride, 8 waves/block

  // layer 1: din=15, H*C=128, ELU
  gemm_dual_kernel<128, 15><<<g128, 128, 0, stream>>>(x, P[0], P[1], P[2], P[3], xl, xr, N);
  agg_kernel<16><<<agrid, 512, 0, stream>>>(xl, xr, base, deg, csr_pack, P[4], P[5], P[6], hA,
                                            nullptr, nullptr, nullptr, N, 1);
  // layer 2: din=128, ELU
  gemm_dual_kernel<128, 128><<<g128, 128, 0, stream>>>(hA, P[7], P[8], P[9], P[10], xl, xr, N);
  agg_kernel<16><<<agrid, 512, 0, stream>>>(xl, xr, base, deg, csr_pack, P[11], P[12], P[13], hB,
                                            nullptr, nullptr, nullptr, N, 1);
  // layer 3: din=128, ELU
  gemm_dual_kernel<128, 128><<<g128, 128, 0, stream>>>(hB, P[14], P[15], P[16], P[17], xl, xr, N);
  agg_kernel<16><<<agrid, 512, 0, stream>>>(xl, xr, base, deg, csr_pack, P[18], P[19], P[20], hA,
                                            nullptr, nullptr, nullptr, N, 1);
  // layer 4: din=128, H*C=64, no ELU + fused final linear 64->1
  gemm_dual_kernel<64, 128><<<g64, 128, 0, stream>>>(hA, P[21], P[22], P[23], P[24], xl, xr, N);
  agg_kernel<8><<<agrid, 512, 0, stream>>>(xl, xr, base, deg, csr_pack, P[25], P[26], P[27], hB,
                                           Wlin, blin, (float*)d_out, N, 0);
}